// Round 6
// baseline (586.883 us; speedup 1.0000x reference)
//
#include <hip/hip_runtime.h>
#include <math.h>

// Problem: N=8192 fp32. out = r_inv[:,None] * (a*b + I), r_inv = 1/rowsum(a*b+I), inf->0.
//
// History:
//  - R0 (191 us): remat -> 1.28 GB vmem.      R1 (210): pin -> scratch spill.
//  - R2 (214, 39% occ): LDS stash, min traffic. R3 (192, 78%): bigger block.
//  - R4 (191, 76%): full DMA staging, MLP by construction. STILL 191.
//  - Invariant across ALL rounds: 768 MiB L2-miss (fabric) traffic / 191 us
//    = 4.0 TB/s, while m13 copy does 6.3. The one shared structural trait:
//    per-block read-all -> barrier -> write-all phases, no R/W overlap, cold
//    start per block. A copy overlaps loads+stores continuously.
//  - R5: persistent-block pipeline; compile failed (static-initialized array
//    of LDS-derived pointers -> addrspacecast in static initializer).
//  - R6 (this): same design, pointers computed arithmetically instead of via
//    pointer arrays. 256 persistent blocks (1/CU), 32 rows each (strided by
//    256 -> dense moving front). Double-buffered DMA staging of both rows
//    (128 KiB dynamic LDS). Counted vmcnt (steady vmcnt(6)) + RAW s_barrier
//    -- never __syncthreads() (which drains vmcnt(0) and kills the pipe).
//    B refilled right after the rowsum barrier, A after stores: reads for
//    row k+2 are in flight during compute+store of row k.

#define NDIM 8192
#define BLOCK 1024
#define WAVES (BLOCK / 64)                        // 16
#define GRID 256
#define RPB (NDIM / GRID)                         // 32 rows per block
#define ROW_BYTES (NDIM * 4)                      // 32768
#define F4_PER_THREAD (NDIM / 4 / BLOCK)          // 2
#define CHUNK_BYTES 1024                          // one wave-DMA: 64 lanes x 16 B
#define CHUNKS_PER_MAT (ROW_BYTES / CHUNK_BYTES)  // 32
#define CPW (CHUNKS_PER_MAT / WAVES)              // 2 chunks per wave per matrix
#define SMEM_BYTES (4 * 32768)                    // A0 A1 B0 B1

typedef float f32x4 __attribute__((ext_vector_type(4)));
typedef __attribute__((address_space(3))) unsigned int lds_u32;
typedef const __attribute__((address_space(1))) unsigned int glb_u32;

__device__ __forceinline__ void dma16(const void* g, void* lds) {
    // lane l: 16 B from its own global addr into (uniform lds base + l*16)
    __builtin_amdgcn_global_load_lds((glb_u32*)g, (lds_u32*)lds, 16, 0, 0);
}

__global__ __launch_bounds__(BLOCK) void row_normalize_kernel(
    const float* __restrict__ a,
    const float* __restrict__ b,
    float* __restrict__ out)
{
    extern __shared__ char smem[];
    __shared__ double wave_sums[WAVES];

    const int tid  = threadIdx.x;
    const int lane = tid & 63;
    const int wave = tid >> 6;
    const int bid  = blockIdx.x;

    // Buffer layout in smem: [A0 | A1 | B0 | B1], 32 KiB each.
    // Addresses computed arithmetically (no pointer arrays: R5 compile bug).

    // Stage one matrix-row (32 KiB) for logical row k into dst: 2 DMA per wave.
    auto dmaMat = [&](const float* src, int k, char* dst) {
        const size_t row = (size_t)(bid + k * GRID);
        const char* g = (const char*)src + row * (size_t)ROW_BYTES;
#pragma unroll
        for (int j = 0; j < CPW; ++j) {
            const int off = (wave * CPW + j) * CHUNK_BYTES;   // wave-uniform
            dma16(g + off + lane * 16, dst + off);
        }
    };

    // Prologue: rows k=0,1 in flight (8 DMA per wave).
    dmaMat(a, 0, smem);                 dmaMat(b, 0, smem + 65536);
    dmaMat(a, 1, smem + 32768);         dmaMat(b, 1, smem + 98304);

    for (int k = 0; k < RPB; ++k) {
        const int par = k & 1;
        const int row = bid + k * GRID;
        char* const pa = smem + par * 32768;            // A[par]
        char* const pb = smem + 65536 + par * 32768;    // B[par]

        // Barrier 1: row k's DMA landed. Counted vmcnt keeps row k+1 (and the
        // just-issued k+2 pieces + store acks) in flight across the barrier.
        // Steady-state outstanding/wave: [B(k):2, st(k-2):2, A(k):2,
        // B(k+1):2, st(k-1):2, A(k+1):2] -> vmcnt(6) drains through A(k).
        if (k == 0)            asm volatile("s_waitcnt vmcnt(4)\ns_barrier" ::: "memory");
        else if (k == RPB - 1) asm volatile("s_waitcnt vmcnt(0)\ns_barrier" ::: "memory");
        else                   asm volatile("s_waitcnt vmcnt(6)\ns_barrier" ::: "memory");
        __builtin_amdgcn_sched_barrier(0);

        const f32x4* A4 = (const f32x4*)pa;
        const f32x4* B4 = (const f32x4*)pb;
        f32x4*       P4 = (f32x4*)pa;                 // product in place over A

        double sum = 0.0;
#pragma unroll
        for (int i = 0; i < F4_PER_THREAD; ++i) {
            const int idx = tid + i * BLOCK;
            f32x4 p = A4[idx] * B4[idx];
            const int col0 = idx << 2;
            if ((unsigned)(row - col0) < 4u) {        // identity diag
                if      (row == col0)     p.x += 1.0f;
                else if (row == col0 + 1) p.y += 1.0f;
                else if (row == col0 + 2) p.z += 1.0f;
                else                      p.w += 1.0f;
            }
            P4[idx] = p;                              // thread-private stash
            sum += (double)p.x + (double)p.y + (double)p.z + (double)p.w;
        }

#pragma unroll
        for (int off = 32; off > 0; off >>= 1)
            sum += __shfl_down(sum, off, 64);
        if (lane == 0) wave_sums[wave] = sum;

        // Barrier 2: wave_sums visible. Raw barrier: vmem stays in flight.
        asm volatile("s_waitcnt lgkmcnt(0)\ns_barrier" ::: "memory");
        __builtin_amdgcn_sched_barrier(0);

        // B[par] fully consumed -> refill with row k+2's B now (overlaps the
        // rest of this iteration: total-sum, scale, store).
        if (k + 2 < RPB) dmaMat(b, k + 2, pb);

        double total = 0.0;
#pragma unroll
        for (int w = 0; w < WAVES; ++w) total += wave_sums[w];
        float r_inv = 1.0f / (float)total;
        if (isinf(r_inv)) r_inv = 0.0f;

        f32x4* __restrict__ o4 = (f32x4*)(out + (size_t)row * NDIM);
#pragma unroll
        for (int i = 0; i < F4_PER_THREAD; ++i) {
            const int idx = tid + i * BLOCK;
            f32x4 p = P4[idx];
            p *= r_inv;
            o4[idx] = p;                              // plain store
        }

        // Barrier 3: all waves' ds_reads of A[par] done (store data already in
        // VGPRs) -> safe to overwrite A[par] with row k+2's A.
        asm volatile("s_barrier" ::: "memory");
        __builtin_amdgcn_sched_barrier(0);
        if (k + 2 < RPB) dmaMat(a, k + 2, pa);
    }
}

extern "C" void kernel_launch(void* const* d_in, const int* in_sizes, int n_in,
                              void* d_out, int out_size, void* d_ws, size_t ws_size,
                              hipStream_t stream) {
    const float* a = (const float*)d_in[0];   // estimated_adj
    const float* b = (const float*)d_in[1];   // ori
    float* out = (float*)d_out;

    static bool init = false;
    if (!init) {   // host-side attribute set, not a stream op: graph-capture safe
        (void)hipFuncSetAttribute((const void*)row_normalize_kernel,
                                  hipFuncAttributeMaxDynamicSharedMemorySize, SMEM_BYTES);
        init = true;
    }
    row_normalize_kernel<<<GRID, BLOCK, SMEM_BYTES, stream>>>(a, b, out);
}

// Round 7
// 554.763 us; speedup vs baseline: 1.0579x; 1.0579x over previous
//
#include <hip/hip_runtime.h>
#include <math.h>

// Problem: N=8192 fp32. out = r_inv[:,None] * (a*b + I), r_inv = 1/rowsum(a*b+I), inf->0.
//
// History:
//  - R0 (191 us): remat -> 1.28 GB vmem.      R1 (210): pin -> scratch spill (NT stores confounded).
//  - R2 (214, 39% occ): LDS stash 256thr.     R3 (192, 78%): LDS stash 512thr.
//  - R4 (191, 76%): full DMA staging (MLP by construction).
//  - R6 (195, 40%): persistent blocks + counted-vmcnt pipeline, continuous R/W overlap.
//  - INVARIANT: every structure = 768 MiB demand / ~191 us = 4.2 TB/s combined,
//    vs 6.3 TB/s for a 1:1 copy. MLP/occupancy/traffic/overlap/launch all eliminated.
//  - The untouched component: the LLC. FETCH_SIZE = exactly 50% of read demand
//    every round = random-replacement thrash signature; all 768 MiB transits the
//    Infinity Cache (hits + fills + write allocations). Theory: the LLC path is
//    the 4.2 TB/s choke, while HBM sits at 2.8/6.3.
//  - R7 (this): R3 base + NON-TEMPORAL loads AND stores on all three streams:
//    take the LLC out of the loop, stream straight to/from HBM.
//    Diagnostic: FETCH_SIZE must double to ~512 MiB. dur pred 135-155 if true;
//    if >=185 with FETCH doubled -> pattern roofline, declare next round.

#define NDIM 8192
#define BLOCK 512
#define V4_PER_THREAD (NDIM / 4 / BLOCK)   // 4
#define WAVES (BLOCK / 64)                 // 8

typedef float f32x4 __attribute__((ext_vector_type(4)));

__global__ __launch_bounds__(BLOCK, 8) void row_normalize_kernel(
    const float* __restrict__ a,
    const float* __restrict__ b,
    float* __restrict__ out)
{
    __shared__ f32x4 stash[NDIM / 4];          // 32 KB: the full product row
    __shared__ double wave_sums[WAVES];

    const int row = blockIdx.x;
    const int tid = threadIdx.x;

    const f32x4* __restrict__ a4 = (const f32x4*)(a + (size_t)row * NDIM);
    const f32x4* __restrict__ b4 = (const f32x4*)(b + (size_t)row * NDIM);
    f32x4*       __restrict__ o4 = (f32x4*)(out + (size_t)row * NDIM);

    // Batch all global loads up front; non-temporal: do NOT allocate in LLC.
    f32x4 av[V4_PER_THREAD], bv[V4_PER_THREAD];
#pragma unroll
    for (int i = 0; i < V4_PER_THREAD; ++i)
        av[i] = __builtin_nontemporal_load(a4 + tid + i * BLOCK);   // coalesced
#pragma unroll
    for (int i = 0; i < V4_PER_THREAD; ++i)
        bv[i] = __builtin_nontemporal_load(b4 + tid + i * BLOCK);

    double sum = 0.0;
#pragma unroll
    for (int i = 0; i < V4_PER_THREAD; ++i) {
        const int idx = tid + i * BLOCK;
        f32x4 p = av[i] * bv[i];
        // identity: mx[row][row] += 1
        const int col0 = idx << 2;
        if ((unsigned)(row - col0) < 4u) {
            if      (row == col0)     p.x += 1.0f;
            else if (row == col0 + 1) p.y += 1.0f;
            else if (row == col0 + 2) p.z += 1.0f;
            else                      p.w += 1.0f;
        }
        stash[idx] = p;                        // thread-private stash, b128, conflict-free
        sum += (double)p.x + (double)p.y + (double)p.z + (double)p.w;
    }

    // wave-64 shuffle reduction
#pragma unroll
    for (int off = 32; off > 0; off >>= 1)
        sum += __shfl_down(sum, off, 64);

    const int lane = tid & 63;
    const int wave = tid >> 6;
    if (lane == 0) wave_sums[wave] = sum;
    __syncthreads();

    // Every thread computes the total redundantly (LDS broadcast reads).
    double total = 0.0;
#pragma unroll
    for (int w = 0; w < WAVES; ++w) total += wave_sums[w];
    float r_inv = 1.0f / (float)total;
    if (isinf(r_inv)) r_inv = 0.0f;

#pragma unroll
    for (int i = 0; i < V4_PER_THREAD; ++i) {
        const int idx = tid + i * BLOCK;
        f32x4 p = stash[idx];                  // read back own stash (on-chip)
        p *= r_inv;
        __builtin_nontemporal_store(p, o4 + idx);   // streamed-once: bypass LLC
    }
}

extern "C" void kernel_launch(void* const* d_in, const int* in_sizes, int n_in,
                              void* d_out, int out_size, void* d_ws, size_t ws_size,
                              hipStream_t stream) {
    const float* a = (const float*)d_in[0];   // estimated_adj
    const float* b = (const float*)d_in[1];   // ori
    float* out = (float*)d_out;
    row_normalize_kernel<<<NDIM, BLOCK, 0, stream>>>(a, b, out);
}

// Round 8
// 553.535 us; speedup vs baseline: 1.0602x; 1.0022x over previous
//
#include <hip/hip_runtime.h>
#include <math.h>

// Problem: N=8192 fp32. out = r_inv[:,None] * (a*b + I), r_inv = 1/rowsum(a*b+I), inf->0.
//
// History:
//  - R0-R6 (191-214 us): remat / pin / LDS stash (39% & 78% occ) / DMA staging /
//    persistent-block counted-vmcnt pipeline -- ALL land at ~4.2 TB/s combined.
//    MLP, occupancy, traffic volume, R/W overlap, launch overhead eliminated.
//  - R7 (<161 us, bench 582->554.8): NON-TEMPORAL loads+stores on the R3 base.
//    First real win: the LLC was interposed in all 768 MiB (FETCH = exactly 50%
//    of read demand = thrash signature); nt bypasses it. Kernel now faster than
//    the harness's 1 GiB fills (161-168 us @ 6.5 TB/s write).
//  - R8 (this): NT + MLP-by-construction. R7's base register-serializes loads
//    (VGPR=20), and NT makes every load a full ~900cy HBM miss -> bytes-in-flight
//    is now the binding constraint. Use R4's global_load_lds DMA staging (no dest
//    VGPRs, wave tile in flight back-to-back) with aux=2 (gfx950 CPol NT bit) on
//    the DMA and NT stores on the output. Target: 768 MiB @ ~6 TB/s ~= 130 us.

#define NDIM 8192
#define BLOCK 1024
#define WAVES (BLOCK / 64)                  // 16
#define V4_PER_THREAD (NDIM / 4 / BLOCK)    // 2
#define ROW_BYTES (NDIM * 4)                // 32768
#define CHUNK_BYTES 1024                    // one wave-DMA: 64 lanes x 16 B
#define CHUNKS (ROW_BYTES / CHUNK_BYTES)    // 32
#define CHUNKS_PER_WAVE (CHUNKS / WAVES)    // 2

typedef float f32x4 __attribute__((ext_vector_type(4)));
typedef __attribute__((address_space(3))) unsigned int lds_u32;
typedef const __attribute__((address_space(1))) unsigned int glb_u32;

__device__ __forceinline__ void dma16_nt(const void* g, void* lds) {
    // width=16: lane l loads 16 B from its own gaddr into (uniform lds base + l*16).
    // aux=2 = CPol NT: non-temporal, bypass LLC allocation (the R7 lever).
    __builtin_amdgcn_global_load_lds((glb_u32*)g, (lds_u32*)lds, 16, 0, 2);
}

__global__ __launch_bounds__(BLOCK, 8) void row_normalize_kernel(
    const float* __restrict__ a,
    const float* __restrict__ b,
    float* __restrict__ out)
{
    __shared__ f32x4 bufA[NDIM / 4];        // 32 KiB: a-row, then product (in place)
    __shared__ f32x4 bufB[NDIM / 4];        // 32 KiB: b-row
    __shared__ double wave_sums[WAVES];

    const int row  = blockIdx.x;
    const int tid  = threadIdx.x;
    const int lane = tid & 63;
    const int wave = tid >> 6;

    const char* arow = (const char*)(a + (size_t)row * NDIM);
    const char* brow = (const char*)(b + (size_t)row * NDIM);
    f32x4* __restrict__ o4 = (f32x4*)(out + (size_t)row * NDIM);

    // --- Stage both rows via async NT DMA: no dest VGPRs, full MLP by construction.
#pragma unroll
    for (int k = 0; k < CHUNKS_PER_WAVE; ++k) {
        const int c = wave * CHUNKS_PER_WAVE + k;
        const int goff = c * CHUNK_BYTES + lane * 16;   // per-lane global addr
        dma16_nt(arow + goff, (char*)bufA + c * CHUNK_BYTES);
        dma16_nt(brow + goff, (char*)bufB + c * CHUNK_BYTES);
    }
    asm volatile("s_waitcnt vmcnt(0)" ::: "memory");
    __syncthreads();

    // --- Product + row-sum. Overwrite bufA with the product (thread-private slots).
    double sum = 0.0;
#pragma unroll
    for (int i = 0; i < V4_PER_THREAD; ++i) {
        const int idx = tid + i * BLOCK;
        f32x4 p = bufA[idx] * bufB[idx];
        // identity: mx[row][row] += 1
        const int col0 = idx << 2;
        if ((unsigned)(row - col0) < 4u) {
            if      (row == col0)     p.x += 1.0f;
            else if (row == col0 + 1) p.y += 1.0f;
            else if (row == col0 + 2) p.z += 1.0f;
            else                      p.w += 1.0f;
        }
        bufA[idx] = p;
        sum += (double)p.x + (double)p.y + (double)p.z + (double)p.w;
    }

    // wave-64 shuffle reduction
#pragma unroll
    for (int off = 32; off > 0; off >>= 1)
        sum += __shfl_down(sum, off, 64);

    if (lane == 0) wave_sums[wave] = sum;
    __syncthreads();

    // Every thread computes the total redundantly (LDS broadcast reads).
    double total = 0.0;
#pragma unroll
    for (int w = 0; w < WAVES; ++w) total += wave_sums[w];
    float r_inv = 1.0f / (float)total;
    if (isinf(r_inv)) r_inv = 0.0f;

    // --- Scale + store: pure LDS-read + NT store burst.
#pragma unroll
    for (int i = 0; i < V4_PER_THREAD; ++i) {
        const int idx = tid + i * BLOCK;
        f32x4 p = bufA[idx];
        p *= r_inv;
        __builtin_nontemporal_store(p, o4 + idx);   // streamed-once: bypass LLC
    }
}

extern "C" void kernel_launch(void* const* d_in, const int* in_sizes, int n_in,
                              void* d_out, int out_size, void* d_ws, size_t ws_size,
                              hipStream_t stream) {
    const float* a = (const float*)d_in[0];   // estimated_adj
    const float* b = (const float*)d_in[1];   // ori
    float* out = (float*)d_out;
    row_normalize_kernel<<<NDIM, BLOCK, 0, stream>>>(a, b, out);
}